// Round 2
// baseline (183657.495 us; speedup 1.0000x reference)
//
#include <hip/hip_runtime.h>

#define NB 2
#define NN 4096
#define DIMD 512
#define PD 64
#define KNN 16
#define TOPL 20          // scan depth: 16 + 4 safety margin
#define MROWS (NB*NN)    // 8192

// ---------------- kernel 1: flow (f64) + new_pos + row sq-norm ----------------
__global__ __launch_bounds__(256)
void flow_kernel(const float* __restrict__ states, const float* __restrict__ positions,
                 const float* __restrict__ W_flow, const float* __restrict__ b_flow,
                 float* __restrict__ out_np, float* __restrict__ out_fl,
                 double* __restrict__ npos64, double* __restrict__ sq64,
                 float* __restrict__ sqf)
{
    __shared__ float s_lds[4][DIMD];
    const int t = threadIdx.x;
    const int row0 = blockIdx.x * 4;
    const float4* src = (const float4*)(states + (size_t)row0 * DIMD);
    float4* dst = (float4*)&s_lds[0][0];
    dst[t] = src[t];
    dst[t + 256] = src[t + 256];
    __syncthreads();
    const int lr = t >> 6;      // local row 0..3 (one wave per row)
    const int p  = t & 63;      // output dim
    const int row = row0 + lr;
    const float4* wr = (const float4*)(W_flow + (size_t)p * DIMD);
    const float4* sr = (const float4*)&s_lds[lr][0];
    double acc = 0.0;
    #pragma unroll 8
    for (int d4 = 0; d4 < DIMD/4; ++d4) {
        float4 w4 = wr[d4];
        float4 s4 = sr[d4];
        acc += (double)s4.x * (double)w4.x;
        acc += (double)s4.y * (double)w4.y;
        acc += (double)s4.z * (double)w4.z;
        acc += (double)s4.w * (double)w4.w;
    }
    acc += (double)b_flow[p];
    const size_t g = (size_t)row * PD + p;
    double np_ = (double)positions[g] + 0.1 * acc;
    out_fl[g] = (float)acc;
    out_np[g] = (float)np_;
    npos64[g] = np_;
    double s2 = np_ * np_;
    #pragma unroll
    for (int off = 32; off >= 1; off >>= 1) s2 += __shfl_xor(s2, off);
    if (p == 0) { sq64[row] = s2; sqf[row] = (float)s2; }
}

// ---------------- kernel 2: values = states @ W_val^T + b_val (f32 tiled) ----------------
__global__ __launch_bounds__(256)
void values_gemm(const float* __restrict__ A, const float* __restrict__ W,
                 const float* __restrict__ bias, float* __restrict__ C)
{
    __shared__ float As[16][68];
    __shared__ float Bs[16][68];
    const int t = threadIdx.x;
    const int bm = blockIdx.y, bn = blockIdx.x;
    const int lr  = t >> 2;
    const int lc4 = (t & 3) << 2;
    const int cr = (t >> 4) << 2;
    const int cc = (t & 15) << 2;
    float acc[4][4] = {};
    for (int k0 = 0; k0 < DIMD; k0 += 16) {
        float4 av = *(const float4*)(A + (size_t)(bm*64 + lr)*DIMD + k0 + lc4);
        float4 wv = *(const float4*)(W + (size_t)(bn*64 + lr)*DIMD + k0 + lc4);
        __syncthreads();
        As[lc4+0][lr] = av.x; As[lc4+1][lr] = av.y; As[lc4+2][lr] = av.z; As[lc4+3][lr] = av.w;
        Bs[lc4+0][lr] = wv.x; Bs[lc4+1][lr] = wv.y; Bs[lc4+2][lr] = wv.z; Bs[lc4+3][lr] = wv.w;
        __syncthreads();
        #pragma unroll
        for (int kk = 0; kk < 16; ++kk) {
            float4 a  = *(const float4*)&As[kk][cr];
            float4 b4 = *(const float4*)&Bs[kk][cc];
            acc[0][0] += a.x*b4.x; acc[0][1] += a.x*b4.y; acc[0][2] += a.x*b4.z; acc[0][3] += a.x*b4.w;
            acc[1][0] += a.y*b4.x; acc[1][1] += a.y*b4.y; acc[1][2] += a.y*b4.z; acc[1][3] += a.y*b4.w;
            acc[2][0] += a.z*b4.x; acc[2][1] += a.z*b4.y; acc[2][2] += a.z*b4.z; acc[2][3] += a.z*b4.w;
            acc[3][0] += a.w*b4.x; acc[3][1] += a.w*b4.y; acc[3][2] += a.w*b4.z; acc[3][3] += a.w*b4.w;
        }
    }
    const int colb = bn*64 + cc;
    float4 bb = *(const float4*)(bias + colb);
    #pragma unroll
    for (int i = 0; i < 4; ++i) {
        float4 o;
        o.x = acc[i][0] + bb.x;
        o.y = acc[i][1] + bb.y;
        o.z = acc[i][2] + bb.z;
        o.w = acc[i][3] + bb.w;
        *(float4*)(C + (size_t)(bm*64 + cr + i)*DIMD + colb) = o;
    }
}

// ---------------- kernel 3: f32 scan + exact f64 rescue + context ----------------
__device__ __forceinline__ bool lexless_f(float v, int i, float w, int j) {
    return (v < w) || (v == w && i < j);
}

__device__ __forceinline__ void ins20(float (&v)[TOPL], int (&ix)[TOPL], float d, int m) {
    if (lexless_f(d, m, v[TOPL-1], ix[TOPL-1])) {
        v[TOPL-1] = d; ix[TOPL-1] = m;
        #pragma unroll
        for (int k = TOPL-1; k > 0; --k) {
            if (lexless_f(v[k], ix[k], v[k-1], ix[k-1])) {
                float tv = v[k]; v[k] = v[k-1]; v[k-1] = tv;
                int ti = ix[k]; ix[k] = ix[k-1]; ix[k-1] = ti;
            }
        }
    }
}

__device__ __forceinline__ void merge20(float (&v)[TOPL], int (&ix)[TOPL], int lane, int* out_ix) {
    for (int k = 0; k < TOPL; ++k) {
        float mv = v[0]; int mi = ix[0];
        #pragma unroll
        for (int off = 32; off >= 1; off >>= 1) {
            float ov = __shfl_xor(mv, off);
            int   oi = __shfl_xor(mi, off);
            if (lexless_f(ov, oi, mv, mi)) { mv = ov; mi = oi; }
        }
        if (ix[0] == mi) {   // unique winner pops its head (indices globally distinct)
            #pragma unroll
            for (int k2 = 0; k2 < TOPL-1; ++k2) { v[k2] = v[k2+1]; ix[k2] = ix[k2+1]; }
            v[TOPL-1] = 1e30f; ix[TOPL-1] = 0x7fffffff;
        }
        if (lane == 0) out_ix[k] = mi;
    }
}

__global__ __launch_bounds__(512)
void dist_kernel(const float* __restrict__ npos32, const float* __restrict__ sqf,
                 const double* __restrict__ npos64, const double* __restrict__ sq64,
                 const float* __restrict__ values, float* __restrict__ ctx)
{
    __shared__ float  pbuf[128][68];
    __shared__ float  qbuf[16][68];
    __shared__ float  sqc[128];
    __shared__ int    tk20[16][TOPL];
    __shared__ double dex[16][TOPL];
    __shared__ int    fin_ix[16][KNN];
    __shared__ float  fin_w[16][KNN];

    const int tid  = threadIdx.x;
    const int w    = tid >> 6;
    const int lane = tid & 63;
    const int b  = blockIdx.x >> 8;
    const int n0 = (blockIdx.x & 255) << 4;

    const float* P32 = npos32 + (size_t)b * NN * PD;

    // stage the 16 query rows once
    if (tid < 256) {
        int row = tid >> 4, c4 = (tid & 15) << 2;
        *(float4*)&qbuf[row][c4] = *(const float4*)(P32 + (size_t)(n0 + row) * PD + c4);
    }

    const int nqA = n0 + 2*w, nqB = nqA + 1;
    const float sqA = sqf[b*NN + nqA];
    const float sqB = sqf[b*NN + nqB];

    float lAv[TOPL], lBv[TOPL]; int lAi[TOPL], lBi[TOPL];
    #pragma unroll
    for (int k = 0; k < TOPL; ++k) { lAv[k]=1e30f; lBv[k]=1e30f; lAi[k]=0x7fffffff; lBi[k]=0x7fffffff; }

    for (int c = 0; c < NN; c += 128) {
        __syncthreads();
        #pragma unroll
        for (int i = 0; i < 4; ++i) {
            int j = tid + i*512;            // 0..2047 float4 slots
            int row = j >> 4, c4 = (j & 15) << 2;
            *(float4*)&pbuf[row][c4] = *(const float4*)(P32 + (size_t)(c + row) * PD + c4);
        }
        if (tid < 128) sqc[tid] = sqf[b*NN + c + tid];
        __syncthreads();

        float aA0=0.f, aA1=0.f, aB0=0.f, aB1=0.f;
        const float* qa = qbuf[2*w];
        const float* qb = qbuf[2*w+1];
        #pragma unroll
        for (int k4 = 0; k4 < 16; ++k4) {
            float4 qav = *(const float4*)&qa[k4*4];
            float4 qbv = *(const float4*)&qb[k4*4];
            float4 p0  = *(const float4*)&pbuf[lane][k4*4];
            float4 p1  = *(const float4*)&pbuf[64 + lane][k4*4];
            aA0 += qav.x*p0.x + qav.y*p0.y + qav.z*p0.z + qav.w*p0.w;
            aA1 += qav.x*p1.x + qav.y*p1.y + qav.z*p1.z + qav.w*p1.w;
            aB0 += qbv.x*p0.x + qbv.y*p0.y + qbv.z*p0.z + qbv.w*p0.w;
            aB1 += qbv.x*p1.x + qbv.y*p1.y + qbv.z*p1.z + qbv.w*p1.w;
        }
        const int cand0 = c + lane, cand1 = c + 64 + lane;
        float d2A0 = sqA + sqc[lane]      - 2.f*aA0;
        float d2A1 = sqA + sqc[64+lane]   - 2.f*aA1;
        float d2B0 = sqB + sqc[lane]      - 2.f*aB0;
        float d2B1 = sqB + sqc[64+lane]   - 2.f*aB1;
        if (cand0 != nqA) ins20(lAv, lAi, d2A0, cand0);
        if (cand1 != nqA) ins20(lAv, lAi, d2A1, cand1);
        if (cand0 != nqB) ins20(lBv, lBi, d2B0, cand0);
        if (cand1 != nqB) ins20(lBv, lBi, d2B1, cand1);
    }

    merge20(lAv, lAi, lane, tk20[2*w]);
    merge20(lBv, lBi, lane, tk20[2*w+1]);
    __syncthreads();

    // exact f64 rescue: 16 queries x 20 candidates = 320 pairs
    if (tid < 16*TOPL) {
        int q  = tid / TOPL;
        int ci = tid - q*TOPL;
        int qg = b*NN + n0 + q;
        int cg = b*NN + tk20[q][ci];
        const double* qr = npos64 + (size_t)qg * PD;
        const double* cr = npos64 + (size_t)cg * PD;
        double acc = 0.0;
        #pragma unroll 8
        for (int p = 0; p < PD; p += 2) {
            double2 qv = *(const double2*)(qr + p);
            double2 cv = *(const double2*)(cr + p);
            acc += qv.x*cv.x + qv.y*cv.y;
        }
        dex[q][ci] = sq64[qg] + sq64[cg] - 2.0*acc;
    }
    __syncthreads();

    // exact rank + weights: wave w handles queries 2w (lanes 0-31) and 2w+1 (lanes 32-63)
    {
        int q  = 2*w + (lane >> 5);
        int sl = lane & 31;
        double d2 = (sl < TOPL) ? dex[q][sl] : 1e300;
        int    mi = (sl < TOPL) ? tk20[q][sl] : 0x7fffffff;
        int rank = 0;
        for (int j = 0; j < TOPL; ++j) {
            double dj = __shfl(d2, j, 32);
            int    ij = __shfl(mi, j, 32);
            if (dj < d2 || (dj == d2 && ij < mi)) ++rank;
        }
        double wk = 0.0;
        if (sl < TOPL && rank < KNN) wk = exp(-0.5 * sqrt(fmax(d2, 1e-12)));
        double ws = wk;
        #pragma unroll
        for (int off = 16; off >= 1; off >>= 1) ws += __shfl_xor(ws, off, 32);
        if (sl < TOPL && rank < KNN) {
            fin_ix[q][rank] = mi;
            fin_w[q][rank]  = (float)(wk / (ws + 1e-8));
        }
    }
    __syncthreads();

    // context: 16 queries x 512 dims
    {
        const int q  = tid >> 5;
        const int e0 = (tid & 31) << 4;
        const float* V = values + (size_t)b * NN * DIMD;
        float acc[16] = {};
        for (int k = 0; k < KNN; ++k) {
            int   m  = fin_ix[q][k];
            float wg = fin_w[q][k];
            const float4* vr = (const float4*)(V + (size_t)m * DIMD + e0);
            #pragma unroll
            for (int j = 0; j < 4; ++j) {
                float4 vv = vr[j];
                acc[4*j+0] += wg*vv.x; acc[4*j+1] += wg*vv.y;
                acc[4*j+2] += wg*vv.z; acc[4*j+3] += wg*vv.w;
            }
        }
        float* crow = ctx + (size_t)(b*NN + n0 + q) * DIMD + e0;
        #pragma unroll
        for (int j = 0; j < 4; ++j)
            *(float4*)(crow + 4*j) = make_float4(acc[4*j], acc[4*j+1], acc[4*j+2], acc[4*j+3]);
    }
}

extern "C" void kernel_launch(void* const* d_in, const int* in_sizes, int n_in,
                              void* d_out, int out_size, void* d_ws, size_t ws_size,
                              hipStream_t stream)
{
    (void)in_sizes; (void)n_in; (void)out_size; (void)ws_size;
    const float* states    = (const float*)d_in[0];
    const float* positions = (const float*)d_in[1];
    const float* W_flow    = (const float*)d_in[2];
    const float* b_flow    = (const float*)d_in[3];
    const float* W_val     = (const float*)d_in[4];
    const float* b_val     = (const float*)d_in[5];

    float* out_ctx = (float*)d_out;                       // [B,N,DIM]
    float* out_np  = out_ctx + (size_t)NB*NN*DIMD;        // [B,N,PD]
    float* out_fl  = out_np  + (size_t)NB*NN*PD;          // [B,N,PD]

    float*  values_ws = (float*)d_ws;                                        // 16 MB
    double* npos64    = (double*)((char*)d_ws + (size_t)NB*NN*DIMD*4);       // 4 MB
    double* sq64      = (double*)((char*)npos64 + (size_t)NB*NN*PD*8);       // 64 KB
    float*  sqf       = (float*)((char*)sq64 + (size_t)MROWS*8);             // 32 KB

    hipLaunchKernelGGL(flow_kernel, dim3(MROWS/4), dim3(256), 0, stream,
                       states, positions, W_flow, b_flow, out_np, out_fl, npos64, sq64, sqf);
    hipLaunchKernelGGL(values_gemm, dim3(DIMD/64, MROWS/64), dim3(256), 0, stream,
                       states, W_val, b_val, values_ws);
    hipLaunchKernelGGL(dist_kernel, dim3(512), dim3(512), 0, stream,
                       out_np, sqf, npos64, sq64, values_ws, out_ctx);
}

// Round 3
// 535.579 us; speedup vs baseline: 342.9142x; 342.9142x over previous
//
#include <hip/hip_runtime.h>

#define NB 2
#define NN 4096
#define DIMD 512
#define PD 64
#define KNN 16
#define MROWS (NB*NN)  // 8192

// ---------------- kernel 1: flow (f64) + new_pos hi/lo + p4t + row sq-norm ----------------
__global__ __launch_bounds__(256)
void flow_kernel(const float* __restrict__ states, const float* __restrict__ positions,
                 const float* __restrict__ W_flow, const float* __restrict__ b_flow,
                 float* __restrict__ out_np, float* __restrict__ out_fl,
                 float* __restrict__ npos_lo, float* __restrict__ p4t,
                 double* __restrict__ sq64, float* __restrict__ sqf)
{
    __shared__ float s_lds[4][DIMD];
    const int t = threadIdx.x;
    const int row0 = blockIdx.x * 4;
    const float4* src = (const float4*)(states + (size_t)row0 * DIMD);
    float4* dst = (float4*)&s_lds[0][0];
    dst[t] = src[t];
    dst[t + 256] = src[t + 256];
    __syncthreads();
    const int lr = t >> 6;      // local row 0..3 (one wave per row)
    const int p  = t & 63;      // output dim
    const int row = row0 + lr;
    const float4* wr = (const float4*)(W_flow + (size_t)p * DIMD);
    const float4* sr = (const float4*)&s_lds[lr][0];
    double acc = 0.0;
    #pragma unroll 8
    for (int d4 = 0; d4 < DIMD/4; ++d4) {
        float4 w4 = wr[d4];
        float4 s4 = sr[d4];
        acc += (double)s4.x * (double)w4.x;
        acc += (double)s4.y * (double)w4.y;
        acc += (double)s4.z * (double)w4.z;
        acc += (double)s4.w * (double)w4.w;
    }
    acc += (double)b_flow[p];
    const size_t g = (size_t)row * PD + p;
    double np_ = (double)positions[g] + 0.1 * acc;
    float hi = (float)np_;
    float lo = (float)(np_ - (double)hi);
    out_fl[g]   = (float)acc;
    out_np[g]   = hi;
    npos_lo[g]  = lo;
    const int bb = row >> 12, n = row & (NN - 1);
    p4t[(((size_t)bb*16 + (p >> 2))*NN + n)*4 + (p & 3)] = hi;
    double s2 = np_ * np_;
    #pragma unroll
    for (int off = 32; off >= 1; off >>= 1) s2 += __shfl_xor(s2, off);
    if (p == 0) { sq64[row] = s2; sqf[row] = (float)s2; }
}

// ---------------- kernel 2: values = states @ W_val^T + b_val (f32 tiled) ----------------
__global__ __launch_bounds__(256)
void values_gemm(const float* __restrict__ A, const float* __restrict__ W,
                 const float* __restrict__ bias, float* __restrict__ C)
{
    __shared__ float As[16][68];
    __shared__ float Bs[16][68];
    const int t = threadIdx.x;
    const int bm = blockIdx.y, bn = blockIdx.x;
    const int lr  = t >> 2;
    const int lc4 = (t & 3) << 2;
    const int cr = (t >> 4) << 2;
    const int cc = (t & 15) << 2;
    float acc[4][4] = {};
    for (int k0 = 0; k0 < DIMD; k0 += 16) {
        float4 av = *(const float4*)(A + (size_t)(bm*64 + lr)*DIMD + k0 + lc4);
        float4 wv = *(const float4*)(W + (size_t)(bn*64 + lr)*DIMD + k0 + lc4);
        __syncthreads();
        As[lc4+0][lr] = av.x; As[lc4+1][lr] = av.y; As[lc4+2][lr] = av.z; As[lc4+3][lr] = av.w;
        Bs[lc4+0][lr] = wv.x; Bs[lc4+1][lr] = wv.y; Bs[lc4+2][lr] = wv.z; Bs[lc4+3][lr] = wv.w;
        __syncthreads();
        #pragma unroll
        for (int kk = 0; kk < 16; ++kk) {
            float4 a  = *(const float4*)&As[kk][cr];
            float4 b4 = *(const float4*)&Bs[kk][cc];
            acc[0][0] += a.x*b4.x; acc[0][1] += a.x*b4.y; acc[0][2] += a.x*b4.z; acc[0][3] += a.x*b4.w;
            acc[1][0] += a.y*b4.x; acc[1][1] += a.y*b4.y; acc[1][2] += a.y*b4.z; acc[1][3] += a.y*b4.w;
            acc[2][0] += a.z*b4.x; acc[2][1] += a.z*b4.y; acc[2][2] += a.z*b4.z; acc[2][3] += a.z*b4.w;
            acc[3][0] += a.w*b4.x; acc[3][1] += a.w*b4.y; acc[3][2] += a.w*b4.z; acc[3][3] += a.w*b4.w;
        }
    }
    const int colb = bn*64 + cc;
    float4 bb = *(const float4*)(bias + colb);
    #pragma unroll
    for (int i = 0; i < 4; ++i) {
        float4 o;
        o.x = acc[i][0] + bb.x;
        o.y = acc[i][1] + bb.y;
        o.z = acc[i][2] + bb.z;
        o.w = acc[i][3] + bb.w;
        *(float4*)(C + (size_t)(bm*64 + cr + i)*DIMD + colb) = o;
    }
}

// ---------------- kernel 3: threshold-scan + LDS collect + exact f64 rescue + context ----------------
// Block: 256 thr (4 waves), 16 queries. Wave w: queries (w>>1)*8..+7, candidate half w&1.
// Selection state per query: one f32 threshold. Passers appended to LDS via ds-atomic.
// Exactness: t always > 19th-smallest f32 d2 of candidates seen so far (superset of true
// top-16 with slop 3); exact f64 rescue re-ranks the collected set.
__global__ __launch_bounds__(256, 2)
void dist_kernel(const float* __restrict__ npos32, const float* __restrict__ npos_lo,
                 const float4* __restrict__ p4t, const float* __restrict__ sqf,
                 const double* __restrict__ sq64, const float* __restrict__ values,
                 float* __restrict__ ctx)
{
    __shared__ float  qstage[16][68];
    __shared__ int    col_ix[16][2][128];
    __shared__ float  col_d [16][2][128];
    __shared__ int    ccnt[16][2];
    __shared__ double dex[16][256];
    __shared__ int    fin_ix[16][KNN];
    __shared__ float  fin_w[16][KNN];

    const int tid  = threadIdx.x;
    const int w    = tid >> 6;
    const int lane = tid & 63;
    const int b  = blockIdx.x >> 8;
    const int n0 = (blockIdx.x & 255) << 4;
    const int qg   = (w >> 1) << 3;   // local query base: 0 or 8
    const int half = w & 1;

    if (tid < 32) ccnt[tid >> 1][tid & 1] = 0;
    {
        int row = tid >> 4, c4 = (tid & 15) << 2;
        *(float4*)&qstage[row][c4] =
            *(const float4*)(npos32 + (size_t)(b*NN + n0 + row)*PD + c4);
    }
    __syncthreads();

    float sqq[8]; int qn[8]; float tv[8];
    #pragma unroll
    for (int j = 0; j < 8; ++j) {
        qn[j]  = n0 + qg + j;
        sqq[j] = sqf[b*NN + qn[j]];
        tv[j]  = 1e30f;
    }

    const float4* P4 = p4t + (size_t)b * 16 * NN;

    for (int ch = 0; ch < 8; ++ch) {
        const int cbase = half*2048 + ch*256;
        float a[8][4];
        #pragma unroll
        for (int j = 0; j < 8; ++j)
            #pragma unroll
            for (int s = 0; s < 4; ++s) a[j][s] = 0.f;

        #pragma unroll
        for (int k4 = 0; k4 < 16; ++k4) {
            float4 pv[4];
            #pragma unroll
            for (int s = 0; s < 4; ++s)
                pv[s] = P4[(size_t)k4*NN + cbase + s*64 + lane];
            #pragma unroll
            for (int j = 0; j < 8; ++j) {
                float4 qv = *(const float4*)&qstage[qg + j][k4 << 2];
                #pragma unroll
                for (int s = 0; s < 4; ++s)
                    a[j][s] += qv.x*pv[s].x + qv.y*pv[s].y + qv.z*pv[s].z + qv.w*pv[s].w;
            }
        }
        float sqcv[4];
        #pragma unroll
        for (int s = 0; s < 4; ++s) sqcv[s] = sqf[b*NN + cbase + s*64 + lane];
        #pragma unroll
        for (int j = 0; j < 8; ++j)
            #pragma unroll
            for (int s = 0; s < 4; ++s) {
                float d2 = fmaxf(sqq[j] + sqcv[s] - 2.f*a[j][s], 0.f);
                if (cbase + s*64 + lane == qn[j]) d2 = 1e30f;
                a[j][s] = d2;
            }

        if (ch == 0) {
            // binary-search t0 over this chunk's 256 d2 (int-monotone positive floats)
            #pragma unroll 1
            for (int j = 0; j < 8; ++j) {
                unsigned lo = 0u, hi = 0x7f800000u;
                for (int it = 0; it < 20; ++it) {
                    unsigned mid = (lo + hi) >> 1;
                    float fm = __uint_as_float(mid);
                    int cnt = 0;
                    #pragma unroll
                    for (int s = 0; s < 4; ++s)
                        cnt += __popcll(__ballot(a[j][s] < fm));
                    if (cnt >= 19) hi = mid; else lo = mid;
                }
                tv[j] = __uint_as_float(hi);
            }
        }

        // append passers (chunk 0 included)
        #pragma unroll
        for (int j = 0; j < 8; ++j)
            #pragma unroll
            for (int s = 0; s < 4; ++s) {
                if (a[j][s] < tv[j]) {
                    int slot = atomicAdd(&ccnt[qg + j][half], 1);
                    if (slot < 128) {
                        col_ix[qg + j][half][slot] = cbase + s*64 + lane;
                        col_d [qg + j][half][slot] = a[j][s];
                    }
                }
            }

        // tighten thresholds from own-half collected set
        if (ch == 1 || ch == 3 || ch == 5) {
            #pragma unroll 1
            for (int j = 0; j < 8; ++j) {
                int cnt0 = ccnt[qg + j][half]; if (cnt0 > 128) cnt0 = 128;
                float v0 = (lane      < cnt0) ? col_d[qg + j][half][lane]      : 1e30f;
                float v1 = (64 + lane < cnt0) ? col_d[qg + j][half][64 + lane] : 1e30f;
                unsigned lo = 0u, hi = __float_as_uint(tv[j]);
                for (int it = 0; it < 20; ++it) {
                    unsigned mid = (lo + hi) >> 1;
                    float fm = __uint_as_float(mid);
                    int cnt = __popcll(__ballot(v0 < fm)) + __popcll(__ballot(v1 < fm));
                    if (cnt >= 19) hi = mid; else lo = mid;
                }
                tv[j] = __uint_as_float(hi);
            }
        }
    }
    __syncthreads();

    // exact f64 d2 for collected candidates (positions reconstructed from hi+lo)
    const int qrow_base = b*NN + n0;
    for (int idx = tid; idx < 16*256; idx += 256) {
        int ql = idx >> 8, ci = idx & 255, hf = ci >> 7, sl = ci & 127;
        int cnt = ccnt[ql][hf]; if (cnt > 128) cnt = 128;
        double dv = 1e300;
        if (sl < cnt) {
            int cand = col_ix[ql][hf][sl];
            const float* qh = npos32  + (size_t)(qrow_base + ql)*PD;
            const float* qlo = npos_lo + (size_t)(qrow_base + ql)*PD;
            const float* chp = npos32  + (size_t)(b*NN + cand)*PD;
            const float* clo = npos_lo + (size_t)(b*NN + cand)*PD;
            double acc = 0.0;
            #pragma unroll 8
            for (int p = 0; p < PD; ++p) {
                double qv = (double)qh[p] + (double)qlo[p];
                double cv = (double)chp[p] + (double)clo[p];
                acc += qv * cv;
            }
            dv = sq64[qrow_base + ql] + sq64[b*NN + cand] - 2.0*acc;
        }
        dex[ql][ci] = dv;
    }
    __syncthreads();

    // exact top-16 per query via wave extract-min; weights in f64
    for (int qi = 0; qi < 4; ++qi) {
        const int ql = w + qi*4;
        double ev[4]; int ei[4];
        #pragma unroll
        for (int k = 0; k < 4; ++k) {
            int ci = k*64 + lane;
            int hf = ci >> 7, sl = ci & 127;
            int cnt = ccnt[ql][hf]; if (cnt > 128) cnt = 128;
            ev[k] = dex[ql][ci];
            ei[k] = (sl < cnt) ? col_ix[ql][hf][sl] : 0x7fffffff;
        }
        double wsum = 0.0, mywk = 0.0;
        for (int r = 0; r < KNN; ++r) {
            double mv = ev[0]; int mi = ei[0]; int ms = 0;
            #pragma unroll
            for (int k = 1; k < 4; ++k)
                if (ev[k] < mv || (ev[k] == mv && ei[k] < mi)) { mv = ev[k]; mi = ei[k]; ms = k; }
            double bv = mv; int bi = mi;
            #pragma unroll
            for (int off = 32; off >= 1; off >>= 1) {
                double ov = __shfl_xor(bv, off);
                int    oi = __shfl_xor(bi, off);
                if (ov < bv || (ov == bv && oi < bi)) { bv = ov; bi = oi; }
            }
            if (mi == bi) ev[ms] = 1e300;   // unique winner pops (candidate indices distinct)
            double wk = exp(-0.5 * sqrt(fmax(bv, 1e-12)));
            wsum += wk;
            if (lane == r) mywk = wk;
            if (lane == 0) fin_ix[ql][r] = bi;
        }
        double den = wsum + 1e-8;
        if (lane < KNN) fin_w[ql][lane] = (float)(mywk / den);
    }
    __syncthreads();

    // context: 16 queries x 512 dims (16 threads/query, 32 dims each)
    {
        const int q  = tid >> 4;
        const int e0 = (tid & 15) << 5;
        const float* V = values + (size_t)b*NN*DIMD;
        float acc[32] = {};
        for (int k = 0; k < KNN; ++k) {
            int   m  = fin_ix[q][k];
            float wg = fin_w[q][k];
            const float4* vr = (const float4*)(V + (size_t)m*DIMD + e0);
            #pragma unroll
            for (int t4 = 0; t4 < 8; ++t4) {
                float4 vv = vr[t4];
                acc[4*t4+0] += wg*vv.x; acc[4*t4+1] += wg*vv.y;
                acc[4*t4+2] += wg*vv.z; acc[4*t4+3] += wg*vv.w;
            }
        }
        float* crow = ctx + (size_t)(b*NN + n0 + q)*DIMD + e0;
        #pragma unroll
        for (int t4 = 0; t4 < 8; ++t4)
            *(float4*)(crow + 4*t4) = make_float4(acc[4*t4], acc[4*t4+1], acc[4*t4+2], acc[4*t4+3]);
    }
}

extern "C" void kernel_launch(void* const* d_in, const int* in_sizes, int n_in,
                              void* d_out, int out_size, void* d_ws, size_t ws_size,
                              hipStream_t stream)
{
    (void)in_sizes; (void)n_in; (void)out_size; (void)ws_size;
    const float* states    = (const float*)d_in[0];
    const float* positions = (const float*)d_in[1];
    const float* W_flow    = (const float*)d_in[2];
    const float* b_flow    = (const float*)d_in[3];
    const float* W_val     = (const float*)d_in[4];
    const float* b_val     = (const float*)d_in[5];

    float* out_ctx = (float*)d_out;                       // [B,N,DIM]
    float* out_np  = out_ctx + (size_t)NB*NN*DIMD;        // [B,N,PD]
    float* out_fl  = out_np  + (size_t)NB*NN*PD;          // [B,N,PD]

    char* ws = (char*)d_ws;
    float*  values_ws = (float*)ws;                                   // 16,777,216 B
    float*  npos_lo   = (float*)(ws + (size_t)16777216);              //  2,097,152 B
    double* sq64      = (double*)(ws + (size_t)18874368);             //     65,536 B
    float*  sqf       = (float*)(ws + (size_t)18939904);              //     32,768 B
    float*  p4t       = (float*)(ws + (size_t)18972672);              //  2,097,152 B
    // total 21,069,824 B (same footprint class as round 1, which fit)

    hipLaunchKernelGGL(flow_kernel, dim3(MROWS/4), dim3(256), 0, stream,
                       states, positions, W_flow, b_flow, out_np, out_fl,
                       npos_lo, p4t, sq64, sqf);
    hipLaunchKernelGGL(values_gemm, dim3(DIMD/64, MROWS/64), dim3(256), 0, stream,
                       states, W_val, b_val, values_ws);
    hipLaunchKernelGGL(dist_kernel, dim3(512), dim3(256), 0, stream,
                       out_np, npos_lo, (const float4*)p4t, sqf, sq64, values_ws, out_ctx);
}